// Round 1
// baseline (517.011 us; speedup 1.0000x reference)
//
#include <hip/hip_runtime.h>

#define H 64

// ---------------------------------------------------------------------------
// Detect whether edge_index arrived as int64 (little-endian, values < 2^31 so
// every odd int32 word is 0) or as int32. flag=1 -> int64, flag=0 -> int32.
__global__ void detect_kernel(const int* __restrict__ ei, int* __restrict__ flag) {
    if (threadIdx.x == 0 && blockIdx.x == 0) {
        int any = 0;
        for (int i = 1; i < 257; i += 2) any |= ei[i];
        *flag = (any == 0) ? 1 : 0;
    }
}

// ---------------------------------------------------------------------------
// v3[t][h] = sum_k relu(W4[t][k]) * W3[t][h][k]    (T*H = 256 values)
__global__ void v3_kernel(const float* __restrict__ W3, const float* __restrict__ W4,
                          float* __restrict__ v3) {
    int i = threadIdx.x;                 // one block of 256
    int t = i >> 6, h = i & 63;
    float acc = 0.f;
    for (int k = 0; k < H; ++k) {
        float w4 = W4[t * H + k];
        w4 = w4 > 0.f ? w4 : 0.f;
        acc += w4 * W3[(t * H + h) * H + k];
    }
    v3[i] = acc;
}

// ---------------------------------------------------------------------------
// deg[n] = #edges with idx[e]==n ; S[n] = sum edge_w over those edges.
__global__ void edge_kernel(const int* __restrict__ ei, const float* __restrict__ ew,
                            float* __restrict__ deg, float* __restrict__ S,
                            const int* __restrict__ flag, int E) {
    int e = blockIdx.x * blockDim.x + threadIdx.x;
    if (e >= E) return;
    int f = *flag;                                   // wave-uniform
    int idx = f ? ei[2 * (E + e)] : ei[E + e];       // second row of edge_index
    atomicAdd(&deg[idx], 1.0f);
    atomicAdd(&S[idx], ew[e]);
}

// ---------------------------------------------------------------------------
// Thread-per-node: T layers of 64x64 matvec in registers, then W7/W5 epilogue.
// Also accumulates the graph pool gp[h] = sum_n mu_final[n,h] via wave
// butterfly + one atomic per lane.
__global__ __launch_bounds__(256, 2)
void node_kernel(const float* __restrict__ mu_in, const float* __restrict__ x,
                 const float* __restrict__ W1, const float* __restrict__ W2,
                 const float* __restrict__ W5, const float* __restrict__ W7,
                 const float* __restrict__ deg, const float* __restrict__ S,
                 const float* __restrict__ v3, float* __restrict__ gp,
                 float* __restrict__ out, int N) {
    int n = blockIdx.x * blockDim.x + threadIdx.x;
    bool active = (n < N);

    float m[H];
#pragma unroll
    for (int k = 0; k < H; ++k) m[k] = active ? mu_in[n * H + k] : 0.f;

    float xv = active ? x[n] : 0.f;
    float dg = active ? deg[n] : 0.f;
    float sv = active ? S[n] : 0.f;

    // T = 4 message-passing layers (loop kept rolled for I$; weights uniform
    // -> scalar loads).
    for (int t = 0; t < 4; ++t) {
        const float* __restrict__ w2 = W2 + t * H * H;
        const float* __restrict__ w1 = W1 + t * H;
        const float* __restrict__ vv = v3 + t * H;
        float nw[H];
#pragma unroll
        for (int h = 0; h < H; ++h) {
            float a0 = 0.f, a1 = 0.f, a2 = 0.f, a3 = 0.f;
#pragma unroll
            for (int k = 0; k < H; k += 4) {
                a0 += m[k + 0] * w2[h * H + k + 0];
                a1 += m[k + 1] * w2[h * H + k + 1];
                a2 += m[k + 2] * w2[h * H + k + 2];
                a3 += m[k + 3] * w2[h * H + k + 3];
            }
            float dot = (a0 + a1) + (a2 + a3);
            float val = xv * w1[h] + dg * dot + sv * vv[h];
            nw[h] = val > 0.f ? val : 0.f;
        }
#pragma unroll
        for (int h = 0; h < H; ++h) m[h] = nw[h];
    }

    // Per-node output term: sum_h relu(mu . W7[h,:]) * W5[H+h]
    float pn = 0.f;
#pragma unroll
    for (int h = 0; h < H; ++h) {
        float a0 = 0.f, a1 = 0.f, a2 = 0.f, a3 = 0.f;
#pragma unroll
        for (int k = 0; k < H; k += 4) {
            a0 += m[k + 0] * W7[h * H + k + 0];
            a1 += m[k + 1] * W7[h * H + k + 1];
            a2 += m[k + 2] * W7[h * H + k + 2];
            a3 += m[k + 3] * W7[h * H + k + 3];
        }
        float z = (a0 + a1) + (a2 + a3);
        z = z > 0.f ? z : 0.f;
        pn += z * W5[H + h];
    }
    if (active) out[n] = pn;

    // Graph pool: butterfly-reduce each m[h] across the wave, lane h keeps it,
    // one atomic per lane. Inactive threads have m[h]==0 so they contribute 0.
    int lane = threadIdx.x & 63;
    float red = 0.f;
#pragma unroll
    for (int h = 0; h < H; ++h) {
        float v = m[h];
        v += __shfl_xor(v, 1);
        v += __shfl_xor(v, 2);
        v += __shfl_xor(v, 4);
        v += __shfl_xor(v, 8);
        v += __shfl_xor(v, 16);
        v += __shfl_xor(v, 32);
        if (lane == h) red = v;
    }
    atomicAdd(&gp[lane], red);
}

// ---------------------------------------------------------------------------
// out[n] += C where C = sum_h relu(gp[h]) * W5[h]
__global__ void finalize_kernel(const float* __restrict__ gp, const float* __restrict__ W5,
                                float* __restrict__ out, int N) {
    int n = blockIdx.x * blockDim.x + threadIdx.x;
    float C = 0.f;
#pragma unroll
    for (int h = 0; h < H; ++h) {
        float g = gp[h];
        g = g > 0.f ? g : 0.f;
        C += g * W5[h];
    }
    if (n < N) out[n] += C;
}

// ---------------------------------------------------------------------------
extern "C" void kernel_launch(void* const* d_in, const int* in_sizes, int n_in,
                              void* d_out, int out_size, void* d_ws, size_t ws_size,
                              hipStream_t stream) {
    const float* mu = (const float*)d_in[0];
    const float* x  = (const float*)d_in[1];
    const int*   ei = (const int*)d_in[2];
    const float* ew = (const float*)d_in[3];
    const float* W1 = (const float*)d_in[4];
    const float* W2 = (const float*)d_in[5];
    const float* W3 = (const float*)d_in[6];
    const float* W4 = (const float*)d_in[7];
    const float* W5 = (const float*)d_in[8];
    const float* W7 = (const float*)d_in[9];
    float* out = (float*)d_out;

    const int N = in_sizes[1];   // x is (N,1)
    const int E = in_sizes[3];   // edge_w is (E,1)

    float* ws  = (float*)d_ws;
    float* deg = ws;                 // N
    float* S   = ws + N;             // N
    float* gp  = ws + 2 * N;         // 64
    float* v3  = ws + 2 * N + 64;    // 256
    int*  flag = (int*)(ws + 2 * N + 64 + 256);

    // zero deg, S, gp (ws is poisoned before every launch)
    hipMemsetAsync(ws, 0, (size_t)(2 * N + 64) * sizeof(float), stream);

    detect_kernel<<<1, 64, 0, stream>>>(ei, flag);
    v3_kernel<<<1, 256, 0, stream>>>(W3, W4, v3);
    edge_kernel<<<(E + 255) / 256, 256, 0, stream>>>(ei, ew, deg, S, flag, E);
    node_kernel<<<(N + 255) / 256, 256, 0, stream>>>(mu, x, W1, W2, W5, W7,
                                                     deg, S, v3, gp, out, N);
    finalize_kernel<<<(N + 255) / 256, 256, 0, stream>>>(gp, W5, out, N);
}

// Round 2
// 264.081 us; speedup vs baseline: 1.9578x; 1.9578x over previous
//
#include <hip/hip_runtime.h>

#define H 64
#define NPB 64      // nodes per block
#define STRIDE 68   // padded LDS dword stride (17 x 16B -> float4 aligned)

// ---------------------------------------------------------------------------
// deg[n] = #edges with idx[e]==n ; S[n] = sum edge_w over those edges.
// int64-vs-int32 layout detected in-wave (int64 => odd 32-bit words all 0).
__global__ void edge_kernel(const int* __restrict__ ei, const float* __restrict__ ew,
                            float* __restrict__ deg, float* __restrict__ S, int E) {
    int probe = ei[2 * (threadIdx.x & 63) + 1];          // first 64 odd words
    bool is64 = (__ballot(probe != 0) == 0ULL);          // wave-uniform
    int e = blockIdx.x * blockDim.x + threadIdx.x;
    if (e >= E) return;
    int idx = is64 ? ei[2 * (E + e)] : ei[E + e];        // second row
    atomicAdd(&deg[idx], 1.0f);
    atomicAdd(&S[idx], ew[e]);
}

// ---------------------------------------------------------------------------
// Block = 64 nodes, 256 threads. Thread (l = t&63, hc = t>>6) computes h-range
// [hc*16, hc*16+16) for node l. Node state mu[64] lives in double-buffered
// LDS; weights go through the scalar path (wave-uniform addresses).
__global__ __launch_bounds__(256, 4)
void node_kernel(const float* __restrict__ mu, const float* __restrict__ x,
                 const float* __restrict__ W1, const float* __restrict__ W2,
                 const float* __restrict__ W3, const float* __restrict__ W4,
                 const float* __restrict__ W5, const float* __restrict__ W7,
                 const float* __restrict__ deg, const float* __restrict__ S,
                 float* __restrict__ gp, float* __restrict__ out, int N) {
    __shared__ float bufA[NPB * STRIDE];
    __shared__ float bufB[NPB * STRIDE];
    __shared__ float v3s[4 * H];
    __shared__ float red[4 * 64];

    const int t = threadIdx.x;
    const int l = t & 63;
    const int hc = __builtin_amdgcn_readfirstlane(t >> 6);  // wave-uniform
    const int h0 = hc * 16;
    const int base = blockIdx.x * NPB;
    const int node = base + l;
    const bool valid = node < N;

    // ---- v3[tl][h] = sum_k relu(W4[tl][k]) * W3[tl][h][k]; thread (hc=tl, l=h)
    {
        const float* __restrict__ w3r = W3 + (hc * H + l) * H;
        const float* __restrict__ w4r = W4 + hc * H;
        float acc = 0.f;
#pragma unroll
        for (int k = 0; k < H; ++k) {
            float w4 = fmaxf(w4r[k], 0.f);                  // uniform -> scalar
            acc += w4 * w3r[k];
        }
        v3s[hc * H + l] = acc;
    }

    // ---- cooperative load of the block's mu tile into bufA (coalesced)
    {
        const float* __restrict__ mublk = mu + (size_t)base * H;
        const int maxf = (N - base) * H;
#pragma unroll
        for (int c = 0; c < 4; ++c) {
            int f = (t + 256 * c) * 4;                      // dword index in tile
            float4 v = make_float4(0.f, 0.f, 0.f, 0.f);
            if (f < maxf) v = *(const float4*)(mublk + f);
            int nn = f >> 6, kk = f & 63;
            *(float4*)(&bufA[nn * STRIDE + kk]) = v;
        }
    }
    __syncthreads();

    const float xv = valid ? x[node] : 0.f;
    const float dg = valid ? deg[node] : 0.f;
    const float sv = valid ? S[node] : 0.f;

    float* bcur = bufA;
    float* bnxt = bufB;

    for (int tl = 0; tl < 4; ++tl) {
        const float* __restrict__ w2 = W2 + tl * H * H + h0 * H;  // rows h0..h0+15
        const float* __restrict__ w1 = W1 + tl * H + h0;
        const float* v3p = v3s + tl * H + h0;

        float acc[16];
#pragma unroll
        for (int i = 0; i < 16; ++i) acc[i] = 0.f;

#pragma unroll
        for (int kc = 0; kc < 4; ++kc) {
            const float* mrow = bcur + l * STRIDE + kc * 16;
            float4 m0 = *(const float4*)(mrow + 0);
            float4 m1 = *(const float4*)(mrow + 4);
            float4 m2 = *(const float4*)(mrow + 8);
            float4 m3 = *(const float4*)(mrow + 12);
            float mk[16] = {m0.x, m0.y, m0.z, m0.w, m1.x, m1.y, m1.z, m1.w,
                            m2.x, m2.y, m2.z, m2.w, m3.x, m3.y, m3.z, m3.w};
#pragma unroll
            for (int i = 0; i < 16; ++i) {
                const float* __restrict__ wr = w2 + i * H + kc * 16;
#pragma unroll
                for (int j = 0; j < 16; ++j) acc[i] += mk[j] * wr[j];
            }
        }
#pragma unroll
        for (int i = 0; i < 16; ++i) {
            float val = xv * w1[i] + dg * acc[i] + sv * v3p[i];
            acc[i] = fmaxf(val, 0.f);
        }
#pragma unroll
        for (int i = 0; i < 16; i += 4) {
            float4 v = make_float4(acc[i], acc[i + 1], acc[i + 2], acc[i + 3]);
            *(float4*)(&bnxt[l * STRIDE + h0 + i]) = v;
        }
        __syncthreads();
        float* tmp = bcur; bcur = bnxt; bnxt = tmp;
    }
    // after 4 layers, final mu is in bufA (== bcur)

    // ---- per-node output: pn = sum_h relu(mu . W7[h,:]) * W5[H+h]
    {
        const float* __restrict__ w7 = W7 + h0 * H;
        float acc[16];
#pragma unroll
        for (int i = 0; i < 16; ++i) acc[i] = 0.f;
#pragma unroll
        for (int kc = 0; kc < 4; ++kc) {
            const float* mrow = bcur + l * STRIDE + kc * 16;
            float4 m0 = *(const float4*)(mrow + 0);
            float4 m1 = *(const float4*)(mrow + 4);
            float4 m2 = *(const float4*)(mrow + 8);
            float4 m3 = *(const float4*)(mrow + 12);
            float mk[16] = {m0.x, m0.y, m0.z, m0.w, m1.x, m1.y, m1.z, m1.w,
                            m2.x, m2.y, m2.z, m2.w, m3.x, m3.y, m3.z, m3.w};
#pragma unroll
            for (int i = 0; i < 16; ++i) {
                const float* __restrict__ wr = w7 + i * H + kc * 16;
#pragma unroll
                for (int j = 0; j < 16; ++j) acc[i] += mk[j] * wr[j];
            }
        }
        float pn = 0.f;
#pragma unroll
        for (int i = 0; i < 16; ++i)
            pn += fmaxf(acc[i], 0.f) * W5[H + h0 + i];
        red[hc * 64 + l] = pn;
    }
    __syncthreads();
    if (t < 64) {
        float pn = red[t] + red[64 + t] + red[128 + t] + red[192 + t];
        if (base + t < N) out[base + t] = pn;
    }
    __syncthreads();

    // ---- graph pool: gp[h] += sum over this block's nodes of mu_final[.,h]
    {
        const int l0 = hc * 16;
        float s = 0.f;
#pragma unroll
        for (int r = 0; r < 16; ++r) s += bcur[(l0 + r) * STRIDE + l];
        red[hc * 64 + l] = s;
    }
    __syncthreads();
    if (t < 64) {
        float g = red[t] + red[64 + t] + red[128 + t] + red[192 + t];
        atomicAdd(&gp[t], g);
    }
}

// ---------------------------------------------------------------------------
// out[n] += C where C = sum_h relu(gp[h]) * W5[h]
__global__ void finalize_kernel(const float* __restrict__ gp, const float* __restrict__ W5,
                                float* __restrict__ out, int N) {
    int n = blockIdx.x * blockDim.x + threadIdx.x;
    float C = 0.f;
#pragma unroll
    for (int h = 0; h < H; ++h) C += fmaxf(gp[h], 0.f) * W5[h];
    if (n < N) out[n] += C;
}

// ---------------------------------------------------------------------------
extern "C" void kernel_launch(void* const* d_in, const int* in_sizes, int n_in,
                              void* d_out, int out_size, void* d_ws, size_t ws_size,
                              hipStream_t stream) {
    const float* mu = (const float*)d_in[0];
    const float* x  = (const float*)d_in[1];
    const int*   ei = (const int*)d_in[2];
    const float* ew = (const float*)d_in[3];
    const float* W1 = (const float*)d_in[4];
    const float* W2 = (const float*)d_in[5];
    const float* W3 = (const float*)d_in[6];
    const float* W4 = (const float*)d_in[7];
    const float* W5 = (const float*)d_in[8];
    const float* W7 = (const float*)d_in[9];
    float* out = (float*)d_out;

    const int N = in_sizes[1];   // x is (N,1)
    const int E = in_sizes[3];   // edge_w is (E,1)

    float* ws  = (float*)d_ws;
    float* deg = ws;             // N
    float* S   = ws + N;         // N
    float* gp  = ws + 2 * N;     // 64

    hipMemsetAsync(ws, 0, (size_t)(2 * N + 64) * sizeof(float), stream);

    edge_kernel<<<(E + 255) / 256, 256, 0, stream>>>(ei, ew, deg, S, E);
    node_kernel<<<(N + NPB - 1) / NPB, 256, 0, stream>>>(mu, x, W1, W2, W3, W4,
                                                         W5, W7, deg, S, gp, out, N);
    finalize_kernel<<<(N + 255) / 256, 256, 0, stream>>>(gp, W5, out, N);
}

// Round 3
// 154.736 us; speedup vs baseline: 3.3413x; 1.7067x over previous
//
#include <hip/hip_runtime.h>

#define H 64
#define NPB 64
#define KS 104      // bf16 elems per A-row: 64 data + xv + sv + pad, rows 16B-aligned
#define KSD 52      // dword row stride

typedef short bf16x8 __attribute__((ext_vector_type(8)));
typedef float f32x4 __attribute__((ext_vector_type(4)));

static __device__ __forceinline__ unsigned short f2bf(float f) {
    union { float f; unsigned u; } v; v.f = f;
    unsigned r = v.u + 0x7fffu + ((v.u >> 16) & 1u);
    return (unsigned short)(r >> 16);
}
static __device__ __forceinline__ float bf2f(unsigned short b) {
    union { unsigned u; float f; } v; v.u = ((unsigned)b) << 16;
    return v.f;
}
// split fp32 -> hi + lo bf16 (kills systematic weight-quantization error)
static __device__ __forceinline__ void split8(const float* ff, bf16x8& hi, bf16x8& lo) {
#pragma unroll
    for (int j = 0; j < 8; ++j) {
        unsigned short h = f2bf(ff[j]);
        hi[j] = (short)h;
        lo[j] = (short)f2bf(ff[j] - bf2f(h));
    }
}

// ---------------------------------------------------------------------------
// One fp64 atomic per edge: T[n] = 4096*deg(n) + S(n).  deg <= ~50, S < deg,
// so T < 2^18: both recoverable exactly / to ~1e-10 from the fp64 sum.
__global__ void edge_kernel(const int* __restrict__ ei, const float* __restrict__ ew,
                            double* __restrict__ dS, int E) {
    int probe = ei[2 * (threadIdx.x & 63) + 1];
    bool is64 = (__ballot(probe != 0) == 0ULL);          // wave-uniform
    int e = blockIdx.x * blockDim.x + threadIdx.x;
    if (e >= E) return;
    int idx = is64 ? ei[2 * (E + e)] : ei[E + e];        // second row
    unsafeAtomicAdd(&dS[idx], 4096.0 + (double)ew[e]);
}

// ---------------------------------------------------------------------------
// Block = 64 nodes, 4 waves. Each layer: D[64x64] = A[64x96]*B[96x64] via
// mfma_f32_16x16x32_bf16. A rows: [deg*mu | xv | sv | 0-pad] (bf16, LDS);
// B: [W2^T ; W1 ; v3 ; 0] hi/lo-split bf16 in VGPRs. Wave w owns h-columns
// [16w,16w+16).
__global__ __launch_bounds__(256, 2)
void node_kernel(const float* __restrict__ mu, const float* __restrict__ x,
                 const float* __restrict__ W1, const float* __restrict__ W2,
                 const float* __restrict__ W3, const float* __restrict__ W4,
                 const float* __restrict__ W5, const float* __restrict__ W7,
                 const double* __restrict__ dS, float* __restrict__ gp,
                 float* __restrict__ out, int N) {
    __shared__ unsigned short Ab[2][NPB * KS];
    __shared__ float v3s[4 * H];
    __shared__ float degs[NPB];
    __shared__ float red[4 * NPB];

    const int t = threadIdx.x;
    const int lane = t & 63;
    const int w = __builtin_amdgcn_readfirstlane(t >> 6);   // wave id = h-tile
    const int c = lane & 15;                                // col in 16-tile
    const int q = lane >> 4;                                // k/row quad
    const int hh = 16 * w + c;                              // this lane's h
    const int base = blockIdx.x * NPB;

    // ---- zero both A buffers (pads must be 0)
    {
        unsigned* a = (unsigned*)&Ab[0][0];
        for (int i = t; i < 2 * NPB * KSD; i += 256) a[i] = 0;
    }
    // ---- v3[tl][h] = sum_k relu(W4[tl][k]) * W3[tl][h][k]   (t -> tl=w,h=lane)
    {
        const float* __restrict__ w3r = W3 + (w * H + lane) * H;
        const float* __restrict__ w4r = W4 + w * H;             // uniform -> sload
        float a0 = 0, a1 = 0, a2 = 0, a3 = 0;
#pragma unroll
        for (int k = 0; k < H; k += 4) {
            a0 += fmaxf(w4r[k + 0], 0.f) * w3r[k + 0];
            a1 += fmaxf(w4r[k + 1], 0.f) * w3r[k + 1];
            a2 += fmaxf(w4r[k + 2], 0.f) * w3r[k + 2];
            a3 += fmaxf(w4r[k + 3], 0.f) * w3r[k + 3];
        }
        v3s[w * H + lane] = (a0 + a1) + (a2 + a3);
    }
    __syncthreads();

    // ---- per-node scalars; xv/sv into cols 64/65 of BOTH buffers
    if (t < 64) {
        int node = base + t;
        float dg = 0.f, sv = 0.f, xv = 0.f;
        if (node < N) {
            double T = dS[node];
            double k = floor(T * (1.0 / 4096.0));
            dg = (float)k;
            sv = (float)(T - 4096.0 * k);
            xv = x[node];
        }
        degs[t] = dg;
        unsigned short xb = f2bf(xv), sb = f2bf(sv);
        Ab[0][t * KS + 64] = xb; Ab[0][t * KS + 65] = sb;
        Ab[1][t * KS + 64] = xb; Ab[1][t * KS + 65] = sb;
    }
    __syncthreads();

    // ---- stage A0 = deg[m] * mu (bf16), coalesced
    {
        const float* __restrict__ mublk = mu + (size_t)base * H;
        const int maxf = (N - base) * H;
#pragma unroll
        for (int cc = 0; cc < 4; ++cc) {
            int f = (t + 256 * cc) * 4;
            float4 v = make_float4(0.f, 0.f, 0.f, 0.f);
            if (f < maxf) v = *(const float4*)(mublk + f);
            int m = f >> 6, k = f & 63;
            float dg = degs[m];
            ushort4 b;
            b.x = f2bf(v.x * dg); b.y = f2bf(v.y * dg);
            b.z = f2bf(v.z * dg); b.w = f2bf(v.w * dg);
            *(ushort4*)(&Ab[0][m * KS + k]) = b;
        }
    }
    __syncthreads();

    unsigned short* Acur = &Ab[0][0];
    unsigned short* Anxt = &Ab[1][0];

    for (int tl = 0; tl < 4; ++tl) {
        // B fragments (hi/lo): ksteps k0=0,32 from W2; kstep 2 = [w1; v3; 0..]
        bf16x8 bh[3], bl[3];
#pragma unroll
        for (int s = 0; s < 2; ++s) {
            const float* __restrict__ wp = W2 + (tl * H + hh) * H + s * 32 + q * 8;
            float4 f0 = *(const float4*)(wp);
            float4 f1 = *(const float4*)(wp + 4);
            float ff[8] = {f0.x, f0.y, f0.z, f0.w, f1.x, f1.y, f1.z, f1.w};
            split8(ff, bh[s], bl[s]);
        }
        {
            float ff[8] = {0, 0, 0, 0, 0, 0, 0, 0};
            if (q == 0) { ff[0] = W1[tl * H + hh]; ff[1] = v3s[tl * H + hh]; }
            split8(ff, bh[2], bl[2]);
        }

        f32x4 acc[4];
#pragma unroll
        for (int mt = 0; mt < 4; ++mt)
#pragma unroll
            for (int r = 0; r < 4; ++r) acc[mt][r] = 0.f;

#pragma unroll
        for (int mt = 0; mt < 4; ++mt) {
            const unsigned short* ar = Acur + (mt * 16 + c) * KS;
            bf16x8 a0 = *(const bf16x8*)(ar + q * 8);
            bf16x8 a1 = *(const bf16x8*)(ar + 32 + q * 8);
            bf16x8 a2 = *(const bf16x8*)(ar + 64 + q * 8);
            acc[mt] = __builtin_amdgcn_mfma_f32_16x16x32_bf16(a0, bh[0], acc[mt], 0, 0, 0);
            acc[mt] = __builtin_amdgcn_mfma_f32_16x16x32_bf16(a0, bl[0], acc[mt], 0, 0, 0);
            acc[mt] = __builtin_amdgcn_mfma_f32_16x16x32_bf16(a1, bh[1], acc[mt], 0, 0, 0);
            acc[mt] = __builtin_amdgcn_mfma_f32_16x16x32_bf16(a1, bl[1], acc[mt], 0, 0, 0);
            acc[mt] = __builtin_amdgcn_mfma_f32_16x16x32_bf16(a2, bh[2], acc[mt], 0, 0, 0);
            acc[mt] = __builtin_amdgcn_mfma_f32_16x16x32_bf16(a2, bl[2], acc[mt], 0, 0, 0);
        }

        // epilogue: relu, pre-scale next-layer A rows by deg (not on last layer)
        const bool scale = (tl < 3);
#pragma unroll
        for (int mt = 0; mt < 4; ++mt) {
#pragma unroll
            for (int r = 0; r < 4; ++r) {
                int m = mt * 16 + q * 4 + r;
                float v = fmaxf(acc[mt][r], 0.f);
                if (scale) v *= degs[m];
                Anxt[m * KS + hh] = f2bf(v);
            }
        }
        __syncthreads();
        unsigned short* tmp = Acur; Acur = Anxt; Anxt = tmp;
    }
    // final (unscaled) mu in Acur

    // ---- W7 matmul + per-node term: pn[m] = sum_h relu(mu.W7[h,:]) * W5[64+h]
    {
        bf16x8 bh[2], bl[2];
#pragma unroll
        for (int s = 0; s < 2; ++s) {
            const float* __restrict__ wp = W7 + hh * H + s * 32 + q * 8;
            float4 f0 = *(const float4*)(wp);
            float4 f1 = *(const float4*)(wp + 4);
            float ff[8] = {f0.x, f0.y, f0.z, f0.w, f1.x, f1.y, f1.z, f1.w};
            split8(ff, bh[s], bl[s]);
        }
        f32x4 acc[4];
#pragma unroll
        for (int mt = 0; mt < 4; ++mt)
#pragma unroll
            for (int r = 0; r < 4; ++r) acc[mt][r] = 0.f;
#pragma unroll
        for (int mt = 0; mt < 4; ++mt) {
            const unsigned short* ar = Acur + (mt * 16 + c) * KS;
            bf16x8 a0 = *(const bf16x8*)(ar + q * 8);
            bf16x8 a1 = *(const bf16x8*)(ar + 32 + q * 8);
            acc[mt] = __builtin_amdgcn_mfma_f32_16x16x32_bf16(a0, bh[0], acc[mt], 0, 0, 0);
            acc[mt] = __builtin_amdgcn_mfma_f32_16x16x32_bf16(a0, bl[0], acc[mt], 0, 0, 0);
            acc[mt] = __builtin_amdgcn_mfma_f32_16x16x32_bf16(a1, bh[1], acc[mt], 0, 0, 0);
            acc[mt] = __builtin_amdgcn_mfma_f32_16x16x32_bf16(a1, bl[1], acc[mt], 0, 0, 0);
        }
        float w5v = W5[H + hh];
#pragma unroll
        for (int mt = 0; mt < 4; ++mt) {
#pragma unroll
            for (int r = 0; r < 4; ++r) {
                float v = fmaxf(acc[mt][r], 0.f) * w5v;
                v += __shfl_xor(v, 1);
                v += __shfl_xor(v, 2);
                v += __shfl_xor(v, 4);
                v += __shfl_xor(v, 8);
                if (c == 0) red[w * 64 + mt * 16 + q * 4 + r] = v;
            }
        }
    }
    __syncthreads();
    if (t < 64) {
        float pn = red[t] + red[64 + t] + red[128 + t] + red[192 + t];
        if (base + t < N) out[base + t] = pn;
    }
    __syncthreads();

    // ---- graph pool partials from final mu
    {
        int h = t & 63, mq = t >> 6;
        float s = 0.f;
#pragma unroll
        for (int i = 0; i < 16; ++i) s += bf2f(Acur[(mq * 16 + i) * KS + h]);
        red[t] = s;
    }
    __syncthreads();
    if (t < 64) {
        float g = red[t] + red[64 + t] + red[128 + t] + red[192 + t];
        unsafeAtomicAdd(&gp[t], g);
    }
}

// ---------------------------------------------------------------------------
__global__ void finalize_kernel(const float* __restrict__ gp, const float* __restrict__ W5,
                                float* __restrict__ out, int N) {
    int n = blockIdx.x * blockDim.x + threadIdx.x;
    float C = 0.f;
#pragma unroll
    for (int h = 0; h < H; ++h) C += fmaxf(gp[h], 0.f) * W5[h];
    if (n < N) out[n] += C;
}

// ---------------------------------------------------------------------------
extern "C" void kernel_launch(void* const* d_in, const int* in_sizes, int n_in,
                              void* d_out, int out_size, void* d_ws, size_t ws_size,
                              hipStream_t stream) {
    const float* mu = (const float*)d_in[0];
    const float* x  = (const float*)d_in[1];
    const int*   ei = (const int*)d_in[2];
    const float* ew = (const float*)d_in[3];
    const float* W1 = (const float*)d_in[4];
    const float* W2 = (const float*)d_in[5];
    const float* W3 = (const float*)d_in[6];
    const float* W4 = (const float*)d_in[7];
    const float* W5 = (const float*)d_in[8];
    const float* W7 = (const float*)d_in[9];
    float* out = (float*)d_out;

    const int N = in_sizes[1];
    const int E = in_sizes[3];

    double* dS = (double*)d_ws;                              // N doubles
    float*  gp = (float*)((char*)d_ws + (size_t)N * 8);      // 64 floats

    hipMemsetAsync(d_ws, 0, (size_t)N * 8 + 64 * 4, stream);

    edge_kernel<<<(E + 255) / 256, 256, 0, stream>>>(ei, ew, dS, E);
    node_kernel<<<(N + NPB - 1) / NPB, 256, 0, stream>>>(mu, x, W1, W2, W3, W4,
                                                         W5, W7, dS, gp, out, N);
    finalize_kernel<<<(N + 255) / 256, 256, 0, stream>>>(gp, W5, out, N);
}

// Round 4
// 150.233 us; speedup vs baseline: 3.4414x; 1.0300x over previous
//
#include <hip/hip_runtime.h>

#define H 64
#define NPB 64
#define KS 104      // bf16 elems per A-row: 64 data + xv + sv + zero-pad; 208B = 13x16B
typedef short bf16x8 __attribute__((ext_vector_type(8)));
typedef float f32x4 __attribute__((ext_vector_type(4)));

static __device__ __forceinline__ unsigned short f2bf(float f) {
    union { float f; unsigned u; } v; v.f = f;
    unsigned r = v.u + 0x7fffu + ((v.u >> 16) & 1u);
    return (unsigned short)(r >> 16);
}
static __device__ __forceinline__ float bf2f(unsigned short b) {
    union { unsigned u; float f; } v; v.u = ((unsigned)b) << 16;
    return v.f;
}
static __device__ __forceinline__ void split8(const float* ff, bf16x8& hi, bf16x8& lo) {
#pragma unroll
    for (int j = 0; j < 8; ++j) {
        unsigned short h = f2bf(ff[j]);
        hi[j] = (short)h;
        lo[j] = (short)f2bf(ff[j] - bf2f(h));
    }
}

// ws layout (bytes): dS [N*8] | gp [256] | Bpre [196608] | W7pre [32768]
// Bpre frag index: ((tl*4+w)*3+s)*128 + hilo*64 + lane   (each entry = 8 bf16)
// W7pre frag index: (w*2+s)*128 + hilo*64 + lane

// ---------------------------------------------------------------------------
// Block 0: build pre-split weight fragments. Blocks 1..: zero dS+gp.
__global__ __launch_bounds__(256)
void prep_kernel(const float* __restrict__ W1, const float* __restrict__ W2,
                 const float* __restrict__ W3, const float* __restrict__ W4,
                 const float* __restrict__ W7, unsigned* __restrict__ zero_base,
                 int zero_dwords, bf16x8* __restrict__ Bp, bf16x8* __restrict__ W7p) {
    const int t = threadIdx.x;
    if (blockIdx.x != 0) {
        int idx = (blockIdx.x - 1) * 256 + t;
        for (int i = idx; i < zero_dwords; i += 64 * 256) zero_base[i] = 0u;
        return;
    }
    __shared__ float v3s[4 * H];
    {   // v3[tl][h] = sum_k relu(W4[tl][k]) * W3[tl][h][k]
        int tl = t >> 6, h = t & 63;
        const float* __restrict__ w3r = W3 + (tl * H + h) * H;
        const float* __restrict__ w4r = W4 + tl * H;
        float a0 = 0, a1 = 0, a2 = 0, a3 = 0;
#pragma unroll
        for (int k = 0; k < H; k += 4) {
            a0 += fmaxf(w4r[k + 0], 0.f) * w3r[k + 0];
            a1 += fmaxf(w4r[k + 1], 0.f) * w3r[k + 1];
            a2 += fmaxf(w4r[k + 2], 0.f) * w3r[k + 2];
            a3 += fmaxf(w4r[k + 3], 0.f) * w3r[k + 3];
        }
        v3s[t] = (a0 + a1) + (a2 + a3);
    }
    __syncthreads();
    const int w = t >> 6, lane = t & 63, c = lane & 15, q = lane >> 4;
    const int hh = 16 * w + c;
    for (int tl = 0; tl < 4; ++tl) {
        const int b3 = (tl * 4 + w) * 3;
        bf16x8 hi, lo;
#pragma unroll
        for (int s = 0; s < 2; ++s) {
            const float* __restrict__ wp = W2 + (tl * H + hh) * H + s * 32 + q * 8;
            float4 f0 = *(const float4*)(wp);
            float4 f1 = *(const float4*)(wp + 4);
            float ff[8] = {f0.x, f0.y, f0.z, f0.w, f1.x, f1.y, f1.z, f1.w};
            split8(ff, hi, lo);
            Bp[(b3 + s) * 128 + lane] = hi;
            Bp[(b3 + s) * 128 + 64 + lane] = lo;
        }
        float ff[8] = {0, 0, 0, 0, 0, 0, 0, 0};
        if (q == 0) { ff[0] = W1[tl * H + hh]; ff[1] = v3s[tl * H + hh]; }
        split8(ff, hi, lo);
        Bp[(b3 + 2) * 128 + lane] = hi;
        Bp[(b3 + 2) * 128 + 64 + lane] = lo;
    }
#pragma unroll
    for (int s = 0; s < 2; ++s) {
        const float* __restrict__ wp = W7 + hh * H + s * 32 + q * 8;
        float4 f0 = *(const float4*)(wp);
        float4 f1 = *(const float4*)(wp + 4);
        float ff[8] = {f0.x, f0.y, f0.z, f0.w, f1.x, f1.y, f1.z, f1.w};
        bf16x8 hi, lo;
        split8(ff, hi, lo);
        W7p[(w * 2 + s) * 128 + lane] = hi;
        W7p[(w * 2 + s) * 128 + 64 + lane] = lo;
    }
}

// ---------------------------------------------------------------------------
// 4 edges/thread; one fp64 atomic per edge packs deg & S: T = 4096*deg + S.
__global__ __launch_bounds__(256)
void edge_kernel(const int* __restrict__ ei, const float* __restrict__ ew,
                 double* __restrict__ dS, int E) {
    int probe = ei[2 * (threadIdx.x & 63) + 1];
    bool is64 = (__ballot(probe != 0) == 0ULL);           // wave-uniform
    int e0 = 4 * (blockIdx.x * blockDim.x + threadIdx.x);
    if (e0 >= E) return;
    if (e0 + 3 < E) {
        float4 wv = *(const float4*)(ew + e0);
        int i0, i1, i2, i3;
        if (is64) {
            int4 a = *(const int4*)(ei + 2 * (E + e0));
            int4 b = *(const int4*)(ei + 2 * (E + e0) + 4);
            i0 = a.x; i1 = a.z; i2 = b.x; i3 = b.z;
        } else {
            int4 a = *(const int4*)(ei + E + e0);
            i0 = a.x; i1 = a.y; i2 = a.z; i3 = a.w;
        }
        unsafeAtomicAdd(&dS[i0], 4096.0 + (double)wv.x);
        unsafeAtomicAdd(&dS[i1], 4096.0 + (double)wv.y);
        unsafeAtomicAdd(&dS[i2], 4096.0 + (double)wv.z);
        unsafeAtomicAdd(&dS[i3], 4096.0 + (double)wv.w);
    } else {
        for (int j = 0; j < 4 && e0 + j < E; ++j) {
            int e = e0 + j;
            int idx = is64 ? ei[2 * (E + e)] : ei[E + e];
            unsafeAtomicAdd(&dS[idx], 4096.0 + (double)ew[e]);
        }
    }
}

// ---------------------------------------------------------------------------
__global__ __launch_bounds__(256, 2)
void node_kernel(const float* __restrict__ mu, const float* __restrict__ x,
                 const float* __restrict__ W5, const bf16x8* __restrict__ Bp,
                 const bf16x8* __restrict__ W7p, const double* __restrict__ dS,
                 float* __restrict__ gp, float* __restrict__ out, int N) {
    __shared__ unsigned short Ab[2][NPB * KS];
    __shared__ float degs[NPB];
    __shared__ float red[4 * NPB];

    const int t = threadIdx.x;
    const int lane = t & 63;
    const int w = __builtin_amdgcn_readfirstlane(t >> 6);
    const int c = lane & 15;
    const int q = lane >> 4;
    const int hh = 16 * w + c;
    const int base = blockIdx.x * NPB;

    // zero only pad cols 66..103 (dwords 33..51) of every row, both buffers
    if (t < 128) {
        int buf = t >> 6, row = t & 63;
        unsigned* p = (unsigned*)&Ab[buf][row * KS];
#pragma unroll
        for (int d = 33; d < 52; ++d) p[d] = 0u;
    }
    // per-node scalars; xv/sv -> cols 64/65 of BOTH buffers
    if (t < 64) {
        int node = base + t;
        float dg = 0.f, sv = 0.f, xv = 0.f;
        if (node < N) {
            double T = dS[node];
            double k = floor(T * (1.0 / 4096.0));
            dg = (float)k;
            sv = (float)(T - 4096.0 * k);
            xv = x[node];
        }
        degs[t] = dg;
        unsigned short xb = f2bf(xv), sb = f2bf(sv);
        Ab[0][t * KS + 64] = xb; Ab[0][t * KS + 65] = sb;
        Ab[1][t * KS + 64] = xb; Ab[1][t * KS + 65] = sb;
    }
    __syncthreads();

    // stage A0 = deg[m] * mu (bf16), coalesced
    {
        const float* __restrict__ mublk = mu + (size_t)base * H;
        const int maxf = (N - base) * H;
#pragma unroll
        for (int cc = 0; cc < 4; ++cc) {
            int f = (t + 256 * cc) * 4;
            float4 v = make_float4(0.f, 0.f, 0.f, 0.f);
            if (f < maxf) v = *(const float4*)(mublk + f);
            int m = f >> 6, k = f & 63;
            float dg = degs[m];
            ushort4 b;
            b.x = f2bf(v.x * dg); b.y = f2bf(v.y * dg);
            b.z = f2bf(v.z * dg); b.w = f2bf(v.w * dg);
            *(ushort4*)(&Ab[0][m * KS + k]) = b;
        }
    }
    __syncthreads();

    unsigned short* Acur = &Ab[0][0];
    unsigned short* Anxt = &Ab[1][0];

    for (int tl = 0; tl < 4; ++tl) {
        const int b3 = (tl * 4 + w) * 3;
        bf16x8 bh0 = Bp[(b3 + 0) * 128 + lane], bl0 = Bp[(b3 + 0) * 128 + 64 + lane];
        bf16x8 bh1 = Bp[(b3 + 1) * 128 + lane], bl1 = Bp[(b3 + 1) * 128 + 64 + lane];
        bf16x8 bh2 = Bp[(b3 + 2) * 128 + lane], bl2 = Bp[(b3 + 2) * 128 + 64 + lane];

        f32x4 acc[4];
#pragma unroll
        for (int mt = 0; mt < 4; ++mt)
#pragma unroll
            for (int r = 0; r < 4; ++r) acc[mt][r] = 0.f;

#pragma unroll
        for (int mt = 0; mt < 4; ++mt) {
            const unsigned short* ar = Acur + (mt * 16 + c) * KS;
            bf16x8 a0 = *(const bf16x8*)(ar + q * 8);
            bf16x8 a1 = *(const bf16x8*)(ar + 32 + q * 8);
            bf16x8 a2 = *(const bf16x8*)(ar + 64 + q * 8);
            acc[mt] = __builtin_amdgcn_mfma_f32_16x16x32_bf16(a0, bh0, acc[mt], 0, 0, 0);
            acc[mt] = __builtin_amdgcn_mfma_f32_16x16x32_bf16(a0, bl0, acc[mt], 0, 0, 0);
            acc[mt] = __builtin_amdgcn_mfma_f32_16x16x32_bf16(a1, bh1, acc[mt], 0, 0, 0);
            acc[mt] = __builtin_amdgcn_mfma_f32_16x16x32_bf16(a1, bl1, acc[mt], 0, 0, 0);
            acc[mt] = __builtin_amdgcn_mfma_f32_16x16x32_bf16(a2, bh2, acc[mt], 0, 0, 0);
            acc[mt] = __builtin_amdgcn_mfma_f32_16x16x32_bf16(a2, bl2, acc[mt], 0, 0, 0);
        }

        const bool scale = (tl < 3);
#pragma unroll
        for (int mt = 0; mt < 4; ++mt) {
#pragma unroll
            for (int r = 0; r < 4; ++r) {
                int m = mt * 16 + q * 4 + r;
                float v = fmaxf(acc[mt][r], 0.f);
                if (scale) v *= degs[m];
                Anxt[m * KS + hh] = f2bf(v);
            }
        }
        __syncthreads();
        unsigned short* tmp = Acur; Acur = Anxt; Anxt = tmp;
    }

    // W7 matmul + per-node term: pn[m] = sum_h relu(mu.W7[h,:]) * W5[64+h]
    {
        bf16x8 bh0 = W7p[(w * 2 + 0) * 128 + lane], bl0 = W7p[(w * 2 + 0) * 128 + 64 + lane];
        bf16x8 bh1 = W7p[(w * 2 + 1) * 128 + lane], bl1 = W7p[(w * 2 + 1) * 128 + 64 + lane];
        f32x4 acc[4];
#pragma unroll
        for (int mt = 0; mt < 4; ++mt)
#pragma unroll
            for (int r = 0; r < 4; ++r) acc[mt][r] = 0.f;
#pragma unroll
        for (int mt = 0; mt < 4; ++mt) {
            const unsigned short* ar = Acur + (mt * 16 + c) * KS;
            bf16x8 a0 = *(const bf16x8*)(ar + q * 8);
            bf16x8 a1 = *(const bf16x8*)(ar + 32 + q * 8);
            acc[mt] = __builtin_amdgcn_mfma_f32_16x16x32_bf16(a0, bh0, acc[mt], 0, 0, 0);
            acc[mt] = __builtin_amdgcn_mfma_f32_16x16x32_bf16(a0, bl0, acc[mt], 0, 0, 0);
            acc[mt] = __builtin_amdgcn_mfma_f32_16x16x32_bf16(a1, bh1, acc[mt], 0, 0, 0);
            acc[mt] = __builtin_amdgcn_mfma_f32_16x16x32_bf16(a1, bl1, acc[mt], 0, 0, 0);
        }
        float w5v = W5[H + hh];
#pragma unroll
        for (int mt = 0; mt < 4; ++mt) {
#pragma unroll
            for (int r = 0; r < 4; ++r) {
                float v = fmaxf(acc[mt][r], 0.f) * w5v;
                v += __shfl_xor(v, 1);
                v += __shfl_xor(v, 2);
                v += __shfl_xor(v, 4);
                v += __shfl_xor(v, 8);
                if (c == 0) red[w * 64 + mt * 16 + q * 4 + r] = v;
            }
        }
    }
    __syncthreads();
    if (t < 64) {
        float pn = red[t] + red[64 + t] + red[128 + t] + red[192 + t];
        if (base + t < N) out[base + t] = pn;
    }
    __syncthreads();

    // graph pool partials from final mu
    {
        int h = t & 63, mq = t >> 6;
        float s = 0.f;
#pragma unroll
        for (int i = 0; i < 16; ++i) s += bf2f(Acur[(mq * 16 + i) * KS + h]);
        red[t] = s;
    }
    __syncthreads();
    if (t < 64) {
        float g = red[t] + red[64 + t] + red[128 + t] + red[192 + t];
        unsafeAtomicAdd(&gp[t], g);
    }
}

// ---------------------------------------------------------------------------
// out[n] += C, C = sum_h relu(gp[h])*W5[h]; one gp read + wave reduce per wave.
__global__ __launch_bounds__(256)
void finalize_kernel(const float* __restrict__ gp, const float* __restrict__ W5,
                     float* __restrict__ out, int N) {
    int lane = threadIdx.x & 63;
    float v = fmaxf(gp[lane], 0.f) * W5[lane];
    v += __shfl_xor(v, 1);
    v += __shfl_xor(v, 2);
    v += __shfl_xor(v, 4);
    v += __shfl_xor(v, 8);
    v += __shfl_xor(v, 16);
    v += __shfl_xor(v, 32);
    int n = blockIdx.x * blockDim.x + threadIdx.x;
    if (n < N) out[n] += v;
}

// ---------------------------------------------------------------------------
extern "C" void kernel_launch(void* const* d_in, const int* in_sizes, int n_in,
                              void* d_out, int out_size, void* d_ws, size_t ws_size,
                              hipStream_t stream) {
    const float* mu = (const float*)d_in[0];
    const float* x  = (const float*)d_in[1];
    const int*   ei = (const int*)d_in[2];
    const float* ew = (const float*)d_in[3];
    const float* W1 = (const float*)d_in[4];
    const float* W2 = (const float*)d_in[5];
    const float* W3 = (const float*)d_in[6];
    const float* W4 = (const float*)d_in[7];
    const float* W5 = (const float*)d_in[8];
    const float* W7 = (const float*)d_in[9];
    float* out = (float*)d_out;

    const int N = in_sizes[1];
    const int E = in_sizes[3];

    char* ws = (char*)d_ws;
    double* dS  = (double*)ws;                                  // N*8
    float*  gp  = (float*)(ws + (size_t)N * 8);                 // 256 B
    bf16x8* Bp  = (bf16x8*)(ws + (size_t)N * 8 + 256);          // 196608 B
    bf16x8* W7p = (bf16x8*)(ws + (size_t)N * 8 + 256 + 196608); // 32768 B
    int zero_dwords = N * 2 + 64;

    prep_kernel<<<65, 256, 0, stream>>>(W1, W2, W3, W4, W7, (unsigned*)dS,
                                        zero_dwords, Bp, W7p);
    edge_kernel<<<(E + 1023) / 1024, 256, 0, stream>>>(ei, ew, dS, E);
    node_kernel<<<(N + NPB - 1) / NPB, 256, 0, stream>>>(mu, x, W5, Bp, W7p,
                                                         dS, gp, out, N);
    finalize_kernel<<<(N + 255) / 256, 256, 0, stream>>>(gp, W5, out, N);
}